// Round 9
// baseline (302.391 us; speedup 1.0000x reference)
//
#include <hip/hip_runtime.h>
#include <math.h>

#define BSZ 64
#define NPT 16384
#define SEG 16
#define NFPS 256
#define RCAP 1024        // per-wave compacted-region capacity
#define NLANES 64
#define NTHREADS 128     // 2 waves per block = 1 problem

typedef __attribute__((ext_vector_type(2))) float f32x2;

// Packed f32 ops (VOP3P) — per-element IEEE rn, bit-exact vs scalar.
__device__ __forceinline__ f32x2 pk_add(f32x2 a, f32x2 b) {
    f32x2 d;
    asm("v_pk_add_f32 %0, %1, %2" : "=v"(d) : "v"(a), "v"(b));
    return d;
}
__device__ __forceinline__ f32x2 pk_mul(f32x2 a, f32x2 b) {
    f32x2 d;
    asm("v_pk_mul_f32 %0, %1, %2" : "=v"(d) : "v"(a), "v"(b));
    return d;
}

// One step of wave64 f32 max-reduce-to-lane63; bound_ctrl=1 shifts in 0.0f
// (harmless: real wave max > 0 except measure-zero degeneracies).
template <int CTRL>
__device__ __forceinline__ float dpp_max_f32(float v) {
    const int o = __builtin_amdgcn_update_dpp(0, __float_as_int(v), CTRL, 0xf, 0xf, true);
    return fmaxf(v, __int_as_float(o));
}

// Phase 2, per-wave region scan with compile-time pair count P (shared by both
// waves so the instruction stream & barrier counts match; validity via -inf).
template <int P>
__device__ __forceinline__ void fps_phase2(const float4* __restrict__ pts,
                                           float* __restrict__ out, size_t gp_base,
                                           int cw, int wave, int lane, int start_idx,
                                           volatile float* xv, volatile int* xi) {
    const int rbase = wave * RCAP;
    f32x2 xp[P], yp[P], zp[P];
    float md[2 * P];
    #pragma unroll
    for (int p = 0; p < P; ++p) {
        const int i0 = (2 * p) * NLANES + lane;   // index within own region
        const int i1 = i0 + NLANES;
        const bool v0 = (i0 < cw), v1 = (i1 < cw);
        const float4 q0 = pts[rbase + (v0 ? i0 : 0)];
        const float4 q1 = pts[rbase + (v1 ? i1 : 0)];
        xp[p].x = q0.x; xp[p].y = q1.x;
        yp[p].x = q0.y; yp[p].y = q1.y;
        zp[p].x = q0.z; zp[p].y = q1.z;
        md[2 * p]     = v0 ? INFINITY : -INFINITY;
        md[2 * p + 1] = v1 ? INFINITY : -INFINITY;
    }

    float4 c = pts[start_idx];  // first masked point == argmax(mask)
    for (int t = 0; t < NFPS; ++t) {
        if (wave == 0 && lane < 3)
            out[gp_base + (size_t)t * 3 + lane] = (lane == 0) ? c.x : ((lane == 1) ? c.y : c.z);

        f32x2 ncx; ncx.x = -c.x; ncx.y = -c.x;
        f32x2 ncy; ncy.x = -c.y; ncy.y = -c.y;
        f32x2 ncz; ncz.x = -c.z; ncz.y = -c.z;

        // Pure value pass: bit-exact (dx*dx+dy*dy)+dz*dz (rn, no FMA), md
        // update, running max into 4 independent accumulator chains.
        float a0 = -INFINITY, a1 = -INFINITY, a2 = -INFINITY, a3 = -INFINITY;
        #pragma unroll
        for (int p = 0; p < P; ++p) {
            const f32x2 dx = pk_add(xp[p], ncx);
            const f32x2 dy = pk_add(yp[p], ncy);
            const f32x2 dz = pk_add(zp[p], ncz);
            const f32x2 d = pk_add(pk_add(pk_mul(dx, dx), pk_mul(dy, dy)), pk_mul(dz, dz));
            const float m0 = fminf(md[2 * p], d.x);
            const float m1 = fminf(md[2 * p + 1], d.y);
            md[2 * p] = m0;
            md[2 * p + 1] = m1;
            if (p & 1) { a2 = fmaxf(a2, m0); a3 = fmaxf(a3, m1); }
            else       { a0 = fmaxf(a0, m0); a1 = fmaxf(a1, m1); }
        }
        float best = fmaxf(fmaxf(a0, a1), fmaxf(a2, a3));

        // wave64 value max (fmax/fmin return operand bits exactly -> wv is
        // bit-identical to the winning slot's md value)
        best = dpp_max_f32<0x111>(best);  // row_shr:1
        best = dpp_max_f32<0x112>(best);  // row_shr:2
        best = dpp_max_f32<0x114>(best);  // row_shr:4
        best = dpp_max_f32<0x118>(best);  // row_shr:8
        best = dpp_max_f32<0x142>(best);  // row_bcast:15
        best = dpp_max_f32<0x143>(best);  // row_bcast:31
        const float wv = __int_as_float(__builtin_amdgcn_readlane(__float_as_int(best), 63));

        // Rescan own slots for the winner: 4 parallel descending strided
        // chains (depth ~2P/4) -> lowest matching slot; lowest lane via ballot.
        int mc0 = 0x7fff, mc1 = 0x7fff, mc2 = 0x7fff, mc3 = 0x7fff;
        #pragma unroll
        for (int sl = 2 * P - 1; sl >= 0; --sl) {
            const bool hit = (md[sl] == wv);
            switch (sl & 3) {  // compile-time under full unroll
                case 0: mc0 = hit ? sl : mc0; break;
                case 1: mc1 = hit ? sl : mc1; break;
                case 2: mc2 = hit ? sl : mc2; break;
                case 3: mc3 = hit ? sl : mc3; break;
            }
        }
        const int ms = min(min(mc0, mc1), min(mc2, mc3));

        const unsigned long long bm = __ballot(ms != 0x7fff);
        const int wl = __builtin_amdgcn_readfirstlane(__ffsll((long long)bm) - 1);
        const int wsl = __builtin_amdgcn_readlane(ms, wl & 63);
        const int idx = rbase + wsl * NLANES + (wl & 63);
        const float wvv = (cw == 0) ? -INFINITY : wv;  // empty-region guard

        const int buf = t & 1;  // double-buffered exchange -> 1 barrier/iter
        if (lane == 0) { xv[buf * 2 + wave] = wvv; xi[buf * 2 + wave] = idx; }
        __syncthreads();
        const float v0 = xv[buf * 2 + 0], v1 = xv[buf * 2 + 1];
        const int j0 = xi[buf * 2 + 0], j1 = xi[buf * 2 + 1];
        c = pts[(v1 > v0) ? j1 : j0];   // tie -> wave0 (lower global index)
    }
}

__global__ __launch_bounds__(NTHREADS, 2) void fps_part_kernel(const float* __restrict__ x,
                                                               float* __restrict__ out) {
    // XCD swizzle: all 16 segment-blocks of one batch share blockIdx%8 -> same
    // XCD L2 caches that batch's 256KB slice once.
    const int blk = blockIdx.x;
    const int xcd = blk & 7;
    const int grp = blk >> 3;            // 0..127
    const int b = (xcd << 3) | (grp >> 4);
    const int s = grp & 15;
    const int prob = b * SEG + s;        // logical problem id (output slot)
    const int tid = threadIdx.x;
    const int lane = tid & 63;
    const int wave = tid >> 6;

    __shared__ float4 pts[2 * RCAP];     // [wave0 region | wave1 region]
    __shared__ int cnt_sh[2];
    __shared__ float xv[4];              // [buf][wave] winner value
    __shared__ int xi[4];                // [buf][wave] winner index

    // ---- Phase 1: each wave compacts its own half (wave-coherent, no barriers) ----
    const float4* x4 = (const float4*)x + (size_t)b * NPT + wave * (NPT / 2);
    const float fs = (float)s;
    const unsigned long long lanemask = (1ull << lane) - 1ull;
    int total = 0;

    for (int mc = 0; mc < 16; ++mc) {
        float4 p[8];
        #pragma unroll
        for (int j = 0; j < 8; ++j)
            p[j] = x4[(mc * 8 + j) * NLANES + lane];
        #pragma unroll
        for (int j = 0; j < 8; ++j) {
            const bool pred = (p[j].w == fs);
            const unsigned long long m = __ballot(pred);   // per-wave 64-bit
            const int pos = total + __popcll(m & lanemask);
            if (pred && pos < RCAP) pts[wave * RCAP + pos] = p[j];
            total += __popcll(m);
        }
    }
    const int cw = (total < RCAP) ? total : RCAP;
    if (lane == 0) cnt_sh[wave] = cw;
    __syncthreads();
    const int c0 = cnt_sh[0], c1 = cnt_sh[1];
    const int count = c0 + c1;

    const size_t gp_base = (size_t)prob * NFPS * 3;
    const size_t mask_off = (size_t)BSZ * SEG * NFPS * 3 + (size_t)prob;

    if (count < NFPS) {
        for (int i = tid; i < NFPS * 3; i += NTHREADS) out[gp_base + i] = 0.0f;
        if (tid == 0) out[mask_off] = 0.0f;
        return;
    }
    if (tid == 0) out[mask_off] = 1.0f;

    const int start_idx = (c0 > 0) ? 0 : RCAP;  // first masked point's region
    const int cmx = (c0 > c1) ? c0 : c1;
    const int pmax = (__builtin_amdgcn_readfirstlane(cmx) + 127) >> 7;  // pairs

    if (pmax <= 4)      fps_phase2<4>(pts, out, gp_base, cw, wave, lane, start_idx, xv, xi);
    else if (pmax == 5) fps_phase2<5>(pts, out, gp_base, cw, wave, lane, start_idx, xv, xi);
    else if (pmax == 6) fps_phase2<6>(pts, out, gp_base, cw, wave, lane, start_idx, xv, xi);
    else if (pmax <= 8) fps_phase2<8>(pts, out, gp_base, cw, wave, lane, start_idx, xv, xi);
    else                fps_phase2<16>(pts, out, gp_base, cw, wave, lane, start_idx, xv, xi);
}

extern "C" void kernel_launch(void* const* d_in, const int* in_sizes, int n_in,
                              void* d_out, int out_size, void* d_ws, size_t ws_size,
                              hipStream_t stream) {
    const float* x = (const float*)d_in[0];
    float* out = (float*)d_out;
    fps_part_kernel<<<BSZ * SEG, NTHREADS, 0, stream>>>(x, out);
}